// Round 11
// baseline (446.058 us; speedup 1.0000x reference)
//
#include <hip/hip_runtime.h>
#include <cstddef>

// Problem constants (match reference)
#define Bb   4
#define CI   128
#define CO   128
#define Hh   128
#define Ww   128
#define HW   (Hh*Ww)
#define NOFF 18      // 2*K*K
#define NTAP 9       // K*K
#define KTOT (NTAP*CI)   // 1152

typedef short short8 __attribute__((ext_vector_type(8)));
typedef float floatx4 __attribute__((ext_vector_type(4)));

// bf16 RNE split helpers (no NaN/inf in this data)
__device__ inline unsigned short bf16_rne_bits(float f) {
    unsigned u = __float_as_uint(f);
    unsigned r = u + 0x7FFFu + ((u >> 16) & 1u);
    return (unsigned short)(r >> 16);
}
__device__ inline float bf16_bits_to_f32(unsigned short h) {
    return __uint_as_float((unsigned)h << 16);
}

// ---------------------------------------------------------------------------
// K0: transpose x NCHW -> NHWC
// ---------------------------------------------------------------------------
__global__ __launch_bounds__(256) void k_transpose(const float* __restrict__ x,
                                                   float* __restrict__ xt) {
    __shared__ float tile[32][33];
    int b  = blockIdx.z;
    int c0 = blockIdx.y * 32;
    int p0 = blockIdx.x * 32;
    int tx = threadIdx.x;
    int ty = threadIdx.y;
    const float* xb  = x  + (size_t)b * CI * HW;
    float*       xtb = xt + (size_t)b * HW * CI;
#pragma unroll
    for (int i = 0; i < 4; ++i) {
        int c = c0 + ty + 8 * i;
        tile[ty + 8 * i][tx] = xb[(size_t)c * HW + p0 + tx];
    }
    __syncthreads();
#pragma unroll
    for (int i = 0; i < 4; ++i) {
        int p = p0 + ty + 8 * i;
        xtb[(size_t)p * CI + c0 + tx] = tile[tx][ty + 8 * i];
    }
}

// ---------------------------------------------------------------------------
// K0b: weight layout transforms, all fragment-linear bf16 hi/lo.
//  wofrag (offset conv, N padded to 32):
//    i = ((t*4+ks)*2 + nt)*512 + l*8 + j
//  wfrag (main conv): i = ((t*4+ks)*8 + g)*512 + l*8 + j ;
//    value = w_main[o = g*16+(l&15)][c = ks*32+(l>>4)*8+j][tap t]
// ---------------------------------------------------------------------------
__global__ __launch_bounds__(256) void k_weights(const float* __restrict__ w_off,
                                                 const float* __restrict__ w_main,
                                                 unsigned short* __restrict__ wofh,
                                                 unsigned short* __restrict__ wofl,
                                                 unsigned short* __restrict__ wfrag_hi,
                                                 unsigned short* __restrict__ wfrag_lo) {
    int idx = blockIdx.x * 256 + threadIdx.x;
    int stride = gridDim.x * 256;
    for (int i = idx; i < 9 * 4 * 2 * 512; i += stride) {
        int j  = i & 7;
        int l  = (i >> 3) & 63;
        int nt = (i >> 9) & 1;
        int ks = (i >> 10) & 3;
        int t  = i >> 12;                       // 0..8  (= ky*3+kx)
        int oc = nt * 16 + (l & 15);
        int c  = ks * 32 + (l >> 4) * 8 + j;
        float f = (oc < NOFF) ? w_off[(oc * CI + c) * 9 + t] : 0.f;
        unsigned short hb = bf16_rne_bits(f);
        wofh[i] = hb;
        wofl[i] = bf16_rne_bits(f - bf16_bits_to_f32(hb));
    }
    for (int i = idx; i < CO * KTOT; i += stride) {
        int j  = i & 7;
        int l  = (i >> 3) & 63;
        int g  = (i >> 9) & 7;
        int ks = (i >> 12) & 3;
        int t  = i >> 14;
        int o  = g * 16 + (l & 15);
        int c  = ks * 32 + (l >> 4) * 8 + j;
        float f = w_main[(o * CI + c) * 9 + t];
        unsigned short hb = bf16_rne_bits(f);
        wfrag_hi[i] = hb;
        wfrag_lo[i] = bf16_rne_bits(f - bf16_bits_to_f32(hb));
    }
}

// ---------------------------------------------------------------------------
// K1: offset conv via split-bf16 MFMA + cumsum + sample coords (unchanged).
// ---------------------------------------------------------------------------
__global__ __launch_bounds__(256, 2) void k_offsets(const float* __restrict__ xt,
                                                    const unsigned short* __restrict__ wofh,
                                                    const unsigned short* __restrict__ wofl,
                                                    const float* __restrict__ b_off,
                                                    float2* __restrict__ coords) {
    __shared__ __align__(16) unsigned short ph[3 * 34 * 128];  // 26,112 B
    __shared__ __align__(16) unsigned short pl[3 * 34 * 128];  // 26,112 B
    __shared__ float raw[32][19];                              //  2,432 B
    int blk = blockIdx.x;
    int wt  = blk & 3;
    int h   = (blk >> 2) & 127;
    int b   = blk >> 9;
    int w0  = wt * 32;
    int tid  = threadIdx.x;
    int lane = tid & 63;
    int wave = tid >> 6;

    for (int i = tid; i < 3 * 34 * 64; i += 256) {
        int c2  = i & 63;
        int col = (i >> 6) % 34;
        int r   = i / (34 * 64);
        int gy  = h - 1 + r;
        int gx  = w0 - 1 + col;
        float2 v = make_float2(0.f, 0.f);
        if (gy >= 0 && gy < Hh && gx >= 0 && gx < Ww)
            v = *(const float2*)(xt + (((size_t)b * Hh + gy) * Ww + gx) * CI + c2 * 2);
        unsigned short h0 = bf16_rne_bits(v.x);
        unsigned short h1 = bf16_rne_bits(v.y);
        unsigned l0 = bf16_rne_bits(v.x - bf16_bits_to_f32(h0));
        unsigned l1 = bf16_rne_bits(v.y - bf16_bits_to_f32(h1));
        int byte = (((r * 34 + col) * 128) + c2 * 2) * 2;
        byte ^= (col & 7) << 4;
        *(unsigned*)((char*)ph + byte) = (unsigned)h0 | ((unsigned)h1 << 16);
        *(unsigned*)((char*)pl + byte) = l0 | (l1 << 16);
    }
    __syncthreads();

    int m   = wave & 1;
    int nt  = wave >> 1;
    int l15 = lane & 15, lhi = lane >> 4;
    floatx4 accE = (floatx4){0.f, 0.f, 0.f, 0.f};
    floatx4 accO = (floatx4){0.f, 0.f, 0.f, 0.f};
    const short8* bhp = (const short8*)wofh;
    const short8* blp = (const short8*)wofl;
#pragma unroll
    for (int t = 0; t < 9; ++t) {
        int ki = t / 3, kj = t % 3;
        int colb = m * 16 + l15 + kj;
        int rowoff = (ki * 34 + colb) * 256;
#pragma unroll
        for (int ks = 0; ks < 4; ++ks) {
            int abyte = (rowoff + ks * 64 + lhi * 16) ^ ((colb & 7) << 4);
            short8 Ah = *(const short8*)((char*)ph + abyte);
            short8 Al = *(const short8*)((char*)pl + abyte);
            size_t bi = (size_t)((t * 4 + ks) * 2 + nt) * 64 + lane;
            short8 Bh = bhp[bi];
            short8 Bl = blp[bi];
            floatx4& a = (ks & 1) ? accO : accE;
            a = __builtin_amdgcn_mfma_f32_16x16x32_bf16(Ah, Bh, a, 0, 0, 0);
            a = __builtin_amdgcn_mfma_f32_16x16x32_bf16(Ah, Bl, a, 0, 0, 0);
            a = __builtin_amdgcn_mfma_f32_16x16x32_bf16(Al, Bh, a, 0, 0, 0);
        }
    }
    int oc = nt * 16 + l15;
    if (oc < NOFF) {
        float bo = b_off[oc];
#pragma unroll
        for (int r = 0; r < 4; ++r) {
            int px = m * 16 + lhi * 4 + r;
            raw[px][oc] = (accE[r] + accO[r]) + bo;
        }
    }
    __syncthreads();

    for (int i = tid; i < 32 * NTAP; i += 256) {
        int px = i / NTAP;
        int t  = i % NTAP;
        int ki = t / 3, kj = t % 3;
        float offx = 0.f, offy = 0.f;
        for (int q = 0; q <= ki; ++q) offx += raw[px][q * 6 + kj * 2 + 0];
        for (int q = 0; q <= kj; ++q) offy += raw[px][ki * 6 + q * 2 + 1];
        int wg = w0 + px;
        float xg = -1.0f + 2.0f * (float)wg / 127.0f;
        float yg = -1.0f + 2.0f * (float)h  / 127.0f;
        float gx = xg + offx;
        float gy = yg + offy;
        float ix = ((gx + 1.0f) * (float)Ww - 1.0f) * 0.5f;
        float iy = ((gy + 1.0f) * (float)Hh - 1.0f) * 0.5f;
        coords[(((size_t)b * Hh + h) * Ww + wg) * NTAP + t] = make_float2(ix, iy);
    }
}

// ---------------------------------------------------------------------------
// K2: k_fused — wave-level fused sample+GEMM. Wave = 16 px x 64 o.
// Per tap: bilinear gather (lane=(px,c-octet)) -> v[8] -> bf16 hi/lo short8
// IS the MFMA A-fragment (k_sample's validated layout, kept in regs);
// then per ks: 8 coalesced 1KB B-frag loads (L2-resident wfrag) + 12 MFMAs.
// No LDS / barriers in main loop; no afrag materialization. Sampling is
// duplicated across the 2 o-half waves (VALU was 13% busy - cheap).
// Block = 4 waves = 32 px x 128 o; LDS only for the store-transpose epilogue.
// ---------------------------------------------------------------------------
__global__ __launch_bounds__(256, 3) void k_fused(const float* __restrict__ xt,
                                                  const float2* __restrict__ coords,
                                                  const unsigned short* __restrict__ wfh,
                                                  const unsigned short* __restrict__ wfl,
                                                  const float* __restrict__ b_main,
                                                  float* __restrict__ out) {
    __shared__ __align__(16) float epi[CO * 33];   // 16,896 B (epilogue only)
    int nb  = gridDim.x;                 // 2048
    int blk = blockIdx.x;
    blk = (blk & 7) * (nb >> 3) + (blk >> 3);   // XCD-contiguous remap
    int tid = threadIdx.x, lane = tid & 63, wave = tid >> 6;
    int wave_n = wave & 1;               // o-half (0: o 0..63, 1: o 64..127)
    int wave_m = wave >> 1;              // px-tile within block
    int l15 = lane & 15, lhi = lane >> 4;
    int p0 = blk * 32 + wave_m * 16;     // wave's 16-px tile base
    int p  = p0 + l15;                   // this lane's pixel
    int b  = p0 >> 14;                   // batch (tile never crosses batch)

    const float* xb = xt + (size_t)b * HW * CI + lhi * 8;
    const float2* cb = coords + (size_t)p * NTAP;
    const short8* bhp = (const short8*)wfh + lane;
    const short8* blp = (const short8*)wfl + lane;

    floatx4 acc[4];
#pragma unroll
    for (int n = 0; n < 4; ++n) acc[n] = (floatx4){0.f, 0.f, 0.f, 0.f};

    for (int t = 0; t < NTAP; ++t) {
        float2 co = cb[t];
        float ix = co.x, iy = co.y;
        float fx0 = floorf(ix), fy0 = floorf(iy);
        int x0 = (int)fx0, y0 = (int)fy0;
        int x1 = x0 + 1,   y1 = y0 + 1;
        float wx1 = ix - fx0, wy1 = iy - fy0;
        float wx0 = 1.f - wx1, wy0 = 1.f - wy1;
        bool vx0 = (x0 >= 0) & (x0 < Ww);
        bool vx1 = (x1 >= 0) & (x1 < Ww);
        bool vy0 = (y0 >= 0) & (y0 < Hh);
        bool vy1 = (y1 >= 0) & (y1 < Hh);
        int cx0 = min(max(x0, 0), Ww - 1), cx1 = min(max(x1, 0), Ww - 1);
        int cy0 = min(max(y0, 0), Hh - 1), cy1 = min(max(y1, 0), Hh - 1);
        float w00 = (vy0 && vx0) ? wy0 * wx0 : 0.f;
        float w01 = (vy0 && vx1) ? wy0 * wx1 : 0.f;
        float w10 = (vy1 && vx0) ? wy1 * wx0 : 0.f;
        float w11 = (vy1 && vx1) ? wy1 * wx1 : 0.f;
        const float* r00 = xb + ((size_t)cy0 * Ww + cx0) * CI;
        const float* r01 = xb + ((size_t)cy0 * Ww + cx1) * CI;
        const float* r10 = xb + ((size_t)cy1 * Ww + cx0) * CI;
        const float* r11 = xb + ((size_t)cy1 * Ww + cx1) * CI;

#pragma unroll
        for (int ks = 0; ks < 4; ++ks) {
            int c = ks * 32;
            float4 a0 = *(const float4*)(r00 + c), a1 = *(const float4*)(r00 + c + 4);
            float4 b0 = *(const float4*)(r01 + c), b1 = *(const float4*)(r01 + c + 4);
            float4 c0 = *(const float4*)(r10 + c), c1 = *(const float4*)(r10 + c + 4);
            float4 d0 = *(const float4*)(r11 + c), d1 = *(const float4*)(r11 + c + 4);
            float v[8];
            v[0] = w00 * a0.x + w01 * b0.x + w10 * c0.x + w11 * d0.x;
            v[1] = w00 * a0.y + w01 * b0.y + w10 * c0.y + w11 * d0.y;
            v[2] = w00 * a0.z + w01 * b0.z + w10 * c0.z + w11 * d0.z;
            v[3] = w00 * a0.w + w01 * b0.w + w10 * c0.w + w11 * d0.w;
            v[4] = w00 * a1.x + w01 * b1.x + w10 * c1.x + w11 * d1.x;
            v[5] = w00 * a1.y + w01 * b1.y + w10 * c1.y + w11 * d1.y;
            v[6] = w00 * a1.z + w01 * b1.z + w10 * c1.z + w11 * d1.z;
            v[7] = w00 * a1.w + w01 * b1.w + w10 * c1.w + w11 * d1.w;
            short8 Ah, Al;
#pragma unroll
            for (int j = 0; j < 8; ++j) {
                unsigned short hb = bf16_rne_bits(v[j]);
                Ah[j] = (short)hb;
                Al[j] = (short)bf16_rne_bits(v[j] - bf16_bits_to_f32(hb));
            }
            short8 Bh[4], Bl[4];
#pragma unroll
            for (int n = 0; n < 4; ++n) {
                size_t bi = (size_t)(((t * 4 + ks) * 8) + wave_n * 4 + n) * 64;
                Bh[n] = bhp[bi];
                Bl[n] = blp[bi];
            }
#pragma unroll
            for (int n = 0; n < 4; ++n)
                acc[n] = __builtin_amdgcn_mfma_f32_16x16x32_bf16(Ah, Bh[n], acc[n], 0, 0, 0);
#pragma unroll
            for (int n = 0; n < 4; ++n)
                acc[n] = __builtin_amdgcn_mfma_f32_16x16x32_bf16(Ah, Bl[n], acc[n], 0, 0, 0);
#pragma unroll
            for (int n = 0; n < 4; ++n)
                acc[n] = __builtin_amdgcn_mfma_f32_16x16x32_bf16(Al, Bh[n], acc[n], 0, 0, 0);
        }
    }

    // ---- epilogue: transpose through LDS for coalesced stores ----
#pragma unroll
    for (int n = 0; n < 4; ++n) {
        int o = wave_n * 64 + n * 16 + l15;
#pragma unroll
        for (int rr = 0; rr < 4; ++rr) {
            int px = wave_m * 16 + lhi * 4 + rr;
            epi[o * 33 + px] = acc[n][rr];
        }
    }
    __syncthreads();
    int p_blk = blk * 32;                // 32 px contiguous within one h-row
    int bb = p_blk >> 14, hw = p_blk & 16383;
    float* ob = out + (size_t)bb * CO * HW + hw;
    for (int i = tid; i < CO * 32; i += 256) {
        int o  = i >> 5;
        int px = i & 31;
        __builtin_nontemporal_store(epi[o * 33 + px] + b_main[o],
                                    &ob[(size_t)o * HW + px]);
    }
}

// ---------------------------------------------------------------------------
extern "C" void kernel_launch(void* const* d_in, const int* in_sizes, int n_in,
                              void* d_out, int out_size, void* d_ws, size_t ws_size,
                              hipStream_t stream) {
    const float* x      = (const float*)d_in[0];
    const float* w_off  = (const float*)d_in[1];
    const float* b_off  = (const float*)d_in[2];
    const float* w_main = (const float*)d_in[3];
    const float* b_main = (const float*)d_in[4];
    float* out = (float*)d_out;

    // workspace layout (bytes):
    //  xt 33,554,432 | coords 4,718,592 | wofrag 2x73,728 | wfrag 2x294,912
    char* base = (char*)d_ws;
    float*  xt     = (float*)base;
    float2* coords = (float2*)(base + 33554432);
    unsigned short* wofh = (unsigned short*)(base + 33554432 + 4718592);
    unsigned short* wofl = wofh + 9 * 4 * 2 * 512;
    unsigned short* wfh  = wofl + 9 * 4 * 2 * 512;
    unsigned short* wfl  = wfh + (size_t)CO * KTOT;

    k_transpose<<<dim3(HW / 32, CI / 32, Bb), dim3(32, 8), 0, stream>>>(x, xt);
    k_weights<<<576, 256, 0, stream>>>(w_off, w_main, wofh, wofl, wfh, wfl);
    k_offsets<<<Bb * Hh * (Ww / 32), 256, 0, stream>>>(xt, wofh, wofl, b_off, coords);
    k_fused<<<Bb * HW / 32, 256, 0, stream>>>(xt, coords, wfh, wfl, b_main, out);
}

// Round 12
// 397.983 us; speedup vs baseline: 1.1208x; 1.1208x over previous
//
#include <hip/hip_runtime.h>
#include <cstddef>

// Problem constants (match reference)
#define Bb   4
#define CI   128
#define CO   128
#define Hh   128
#define Ww   128
#define HW   (Hh*Ww)
#define NOFF 18      // 2*K*K
#define NTAP 9       // K*K
#define KTOT (NTAP*CI)   // 1152

typedef short short8 __attribute__((ext_vector_type(8)));
typedef float floatx4 __attribute__((ext_vector_type(4)));

// bf16 RNE split helpers (no NaN/inf in this data)
__device__ inline unsigned short bf16_rne_bits(float f) {
    unsigned u = __float_as_uint(f);
    unsigned r = u + 0x7FFFu + ((u >> 16) & 1u);
    return (unsigned short)(r >> 16);
}
__device__ inline float bf16_bits_to_f32(unsigned short h) {
    return __uint_as_float((unsigned)h << 16);
}

// ---------------------------------------------------------------------------
// K0: transpose x NCHW -> NHWC
// ---------------------------------------------------------------------------
__global__ __launch_bounds__(256) void k_transpose(const float* __restrict__ x,
                                                   float* __restrict__ xt) {
    __shared__ float tile[32][33];
    int b  = blockIdx.z;
    int c0 = blockIdx.y * 32;
    int p0 = blockIdx.x * 32;
    int tx = threadIdx.x;
    int ty = threadIdx.y;
    const float* xb  = x  + (size_t)b * CI * HW;
    float*       xtb = xt + (size_t)b * HW * CI;
#pragma unroll
    for (int i = 0; i < 4; ++i) {
        int c = c0 + ty + 8 * i;
        tile[ty + 8 * i][tx] = xb[(size_t)c * HW + p0 + tx];
    }
    __syncthreads();
#pragma unroll
    for (int i = 0; i < 4; ++i) {
        int p = p0 + ty + 8 * i;
        xtb[(size_t)p * CI + c0 + tx] = tile[tx][ty + 8 * i];
    }
}

// ---------------------------------------------------------------------------
// K0b: weight layout transforms, all fragment-linear bf16 hi/lo.
// ---------------------------------------------------------------------------
__global__ __launch_bounds__(256) void k_weights(const float* __restrict__ w_off,
                                                 const float* __restrict__ w_main,
                                                 unsigned short* __restrict__ wofh,
                                                 unsigned short* __restrict__ wofl,
                                                 unsigned short* __restrict__ wfrag_hi,
                                                 unsigned short* __restrict__ wfrag_lo) {
    int idx = blockIdx.x * 256 + threadIdx.x;
    int stride = gridDim.x * 256;
    for (int i = idx; i < 9 * 4 * 2 * 512; i += stride) {
        int j  = i & 7;
        int l  = (i >> 3) & 63;
        int nt = (i >> 9) & 1;
        int ks = (i >> 10) & 3;
        int t  = i >> 12;                       // 0..8  (= ky*3+kx)
        int oc = nt * 16 + (l & 15);
        int c  = ks * 32 + (l >> 4) * 8 + j;
        float f = (oc < NOFF) ? w_off[(oc * CI + c) * 9 + t] : 0.f;
        unsigned short hb = bf16_rne_bits(f);
        wofh[i] = hb;
        wofl[i] = bf16_rne_bits(f - bf16_bits_to_f32(hb));
    }
    for (int i = idx; i < CO * KTOT; i += stride) {
        int j  = i & 7;
        int l  = (i >> 3) & 63;
        int g  = (i >> 9) & 7;
        int ks = (i >> 12) & 3;
        int t  = i >> 14;
        int o  = g * 16 + (l & 15);
        int c  = ks * 32 + (l >> 4) * 8 + j;
        float f = w_main[(o * CI + c) * 9 + t];
        unsigned short hb = bf16_rne_bits(f);
        wfrag_hi[i] = hb;
        wfrag_lo[i] = bf16_rne_bits(f - bf16_bits_to_f32(hb));
    }
}

// ---------------------------------------------------------------------------
// K1: offset conv via split-bf16 MFMA + cumsum + sample coords (unchanged).
// ---------------------------------------------------------------------------
__global__ __launch_bounds__(256, 2) void k_offsets(const float* __restrict__ xt,
                                                    const unsigned short* __restrict__ wofh,
                                                    const unsigned short* __restrict__ wofl,
                                                    const float* __restrict__ b_off,
                                                    float2* __restrict__ coords) {
    __shared__ __align__(16) unsigned short ph[3 * 34 * 128];  // 26,112 B
    __shared__ __align__(16) unsigned short pl[3 * 34 * 128];  // 26,112 B
    __shared__ float raw[32][19];                              //  2,432 B
    int blk = blockIdx.x;
    int wt  = blk & 3;
    int h   = (blk >> 2) & 127;
    int b   = blk >> 9;
    int w0  = wt * 32;
    int tid  = threadIdx.x;
    int lane = tid & 63;
    int wave = tid >> 6;

    for (int i = tid; i < 3 * 34 * 64; i += 256) {
        int c2  = i & 63;
        int col = (i >> 6) % 34;
        int r   = i / (34 * 64);
        int gy  = h - 1 + r;
        int gx  = w0 - 1 + col;
        float2 v = make_float2(0.f, 0.f);
        if (gy >= 0 && gy < Hh && gx >= 0 && gx < Ww)
            v = *(const float2*)(xt + (((size_t)b * Hh + gy) * Ww + gx) * CI + c2 * 2);
        unsigned short h0 = bf16_rne_bits(v.x);
        unsigned short h1 = bf16_rne_bits(v.y);
        unsigned l0 = bf16_rne_bits(v.x - bf16_bits_to_f32(h0));
        unsigned l1 = bf16_rne_bits(v.y - bf16_bits_to_f32(h1));
        int byte = (((r * 34 + col) * 128) + c2 * 2) * 2;
        byte ^= (col & 7) << 4;
        *(unsigned*)((char*)ph + byte) = (unsigned)h0 | ((unsigned)h1 << 16);
        *(unsigned*)((char*)pl + byte) = l0 | (l1 << 16);
    }
    __syncthreads();

    int m   = wave & 1;
    int nt  = wave >> 1;
    int l15 = lane & 15, lhi = lane >> 4;
    floatx4 accE = (floatx4){0.f, 0.f, 0.f, 0.f};
    floatx4 accO = (floatx4){0.f, 0.f, 0.f, 0.f};
    const short8* bhp = (const short8*)wofh;
    const short8* blp = (const short8*)wofl;
#pragma unroll
    for (int t = 0; t < 9; ++t) {
        int ki = t / 3, kj = t % 3;
        int colb = m * 16 + l15 + kj;
        int rowoff = (ki * 34 + colb) * 256;
#pragma unroll
        for (int ks = 0; ks < 4; ++ks) {
            int abyte = (rowoff + ks * 64 + lhi * 16) ^ ((colb & 7) << 4);
            short8 Ah = *(const short8*)((char*)ph + abyte);
            short8 Al = *(const short8*)((char*)pl + abyte);
            size_t bi = (size_t)((t * 4 + ks) * 2 + nt) * 64 + lane;
            short8 Bh = bhp[bi];
            short8 Bl = blp[bi];
            floatx4& a = (ks & 1) ? accO : accE;
            a = __builtin_amdgcn_mfma_f32_16x16x32_bf16(Ah, Bh, a, 0, 0, 0);
            a = __builtin_amdgcn_mfma_f32_16x16x32_bf16(Ah, Bl, a, 0, 0, 0);
            a = __builtin_amdgcn_mfma_f32_16x16x32_bf16(Al, Bh, a, 0, 0, 0);
        }
    }
    int oc = nt * 16 + l15;
    if (oc < NOFF) {
        float bo = b_off[oc];
#pragma unroll
        for (int r = 0; r < 4; ++r) {
            int px = m * 16 + lhi * 4 + r;
            raw[px][oc] = (accE[r] + accO[r]) + bo;
        }
    }
    __syncthreads();

    for (int i = tid; i < 32 * NTAP; i += 256) {
        int px = i / NTAP;
        int t  = i % NTAP;
        int ki = t / 3, kj = t % 3;
        float offx = 0.f, offy = 0.f;
        for (int q = 0; q <= ki; ++q) offx += raw[px][q * 6 + kj * 2 + 0];
        for (int q = 0; q <= kj; ++q) offy += raw[px][ki * 6 + q * 2 + 1];
        int wg = w0 + px;
        float xg = -1.0f + 2.0f * (float)wg / 127.0f;
        float yg = -1.0f + 2.0f * (float)h  / 127.0f;
        float gx = xg + offx;
        float gy = yg + offy;
        float ix = ((gx + 1.0f) * (float)Ww - 1.0f) * 0.5f;
        float iy = ((gy + 1.0f) * (float)Hh - 1.0f) * 0.5f;
        coords[(((size_t)b * Hh + h) * Ww + wg) * NTAP + t] = make_float2(ix, iy);
    }
}

// ---------------------------------------------------------------------------
// K2: k_fused v2 — wave = 16 px x ALL 128 o (no sampling duplication).
// Per tap: issue ALL 32 gather float4 loads into named registers FIRST
// (32-deep MLP, one waitcnt wall per tap), then per ks: blend -> hi/lo
// A-frag -> 16 B-frag loads -> 24 MFMAs into acc[8].
// Block = 4 waves = 64 px. launch_bounds(256,2): ~200 VGPR, 8 waves/CU —
// latency hidden by MLP within the wave, not TLP.
// ---------------------------------------------------------------------------
__global__ __launch_bounds__(256, 2) void k_fused(const float* __restrict__ xt,
                                                  const float2* __restrict__ coords,
                                                  const unsigned short* __restrict__ wfh,
                                                  const unsigned short* __restrict__ wfl,
                                                  const float* __restrict__ b_main,
                                                  float* __restrict__ out) {
    __shared__ __align__(16) float epi[CO * 65];   // 33,280 B (epilogue only)
    int nb  = gridDim.x;                 // 1024
    int blk = blockIdx.x;
    blk = (blk & 7) * (nb >> 3) + (blk >> 3);   // XCD-contiguous remap
    int tid = threadIdx.x, lane = tid & 63, wave = tid >> 6;
    int l15 = lane & 15, lhi = lane >> 4;
    int p0 = blk * 64 + wave * 16;       // wave's 16-px tile base
    int p  = p0 + l15;                   // this lane's pixel
    int b  = p0 >> 14;                   // batch (tile never crosses batch)

    const float* xb = xt + (size_t)b * HW * CI + lhi * 8;
    const float2* cb = coords + (size_t)p * NTAP;
    const short8* bhp = (const short8*)wfh + lane;
    const short8* blp = (const short8*)wfl + lane;

    floatx4 acc[8];
#pragma unroll
    for (int n = 0; n < 8; ++n) acc[n] = (floatx4){0.f, 0.f, 0.f, 0.f};

    for (int t = 0; t < NTAP; ++t) {
        float2 co = cb[t];
        float ix = co.x, iy = co.y;
        float fx0 = floorf(ix), fy0 = floorf(iy);
        int x0 = (int)fx0, y0 = (int)fy0;
        int x1 = x0 + 1,   y1 = y0 + 1;
        float wx1 = ix - fx0, wy1 = iy - fy0;
        float wx0 = 1.f - wx1, wy0 = 1.f - wy1;
        bool vx0 = (x0 >= 0) & (x0 < Ww);
        bool vx1 = (x1 >= 0) & (x1 < Ww);
        bool vy0 = (y0 >= 0) & (y0 < Hh);
        bool vy1 = (y1 >= 0) & (y1 < Hh);
        int cx0 = min(max(x0, 0), Ww - 1), cx1 = min(max(x1, 0), Ww - 1);
        int cy0 = min(max(y0, 0), Hh - 1), cy1 = min(max(y1, 0), Hh - 1);
        float w00 = (vy0 && vx0) ? wy0 * wx0 : 0.f;
        float w01 = (vy0 && vx1) ? wy0 * wx1 : 0.f;
        float w10 = (vy1 && vx0) ? wy1 * wx0 : 0.f;
        float w11 = (vy1 && vx1) ? wy1 * wx1 : 0.f;
        const float* r00 = xb + ((size_t)cy0 * Ww + cx0) * CI;
        const float* r01 = xb + ((size_t)cy0 * Ww + cx1) * CI;
        const float* r10 = xb + ((size_t)cy1 * Ww + cx0) * CI;
        const float* r11 = xb + ((size_t)cy1 * Ww + cx1) * CI;

        // ---- issue ALL 32 gather loads up-front (full-tap MLP) ----
#define GATHER(ks, gA0, gA1, gB0, gB1, gC0, gC1, gD0, gD1)                         \
        float4 gA0 = *(const float4*)(r00 + ks * 32),                              \
               gA1 = *(const float4*)(r00 + ks * 32 + 4);                          \
        float4 gB0 = *(const float4*)(r01 + ks * 32),                              \
               gB1 = *(const float4*)(r01 + ks * 32 + 4);                          \
        float4 gC0 = *(const float4*)(r10 + ks * 32),                              \
               gC1 = *(const float4*)(r10 + ks * 32 + 4);                          \
        float4 gD0 = *(const float4*)(r11 + ks * 32),                              \
               gD1 = *(const float4*)(r11 + ks * 32 + 4);
        GATHER(0, a0A, a0B, b0A, b0B, c0A, c0B, d0A, d0B)
        GATHER(1, a1A, a1B, b1A, b1B, c1A, c1B, d1A, d1B)
        GATHER(2, a2A, a2B, b2A, b2B, c2A, c2B, d2A, d2B)
        GATHER(3, a3A, a3B, b3A, b3B, c3A, c3B, d3A, d3B)
#undef GATHER

        // ---- per ks: blend -> A-frag -> B loads -> 24 MFMAs ----
#define KSTEP(ks, gA0, gA1, gB0, gB1, gC0, gC1, gD0, gD1)                          \
        {                                                                          \
            float v[8];                                                            \
            v[0] = w00 * gA0.x + w01 * gB0.x + w10 * gC0.x + w11 * gD0.x;          \
            v[1] = w00 * gA0.y + w01 * gB0.y + w10 * gC0.y + w11 * gD0.y;          \
            v[2] = w00 * gA0.z + w01 * gB0.z + w10 * gC0.z + w11 * gD0.z;          \
            v[3] = w00 * gA0.w + w01 * gB0.w + w10 * gC0.w + w11 * gD0.w;          \
            v[4] = w00 * gA1.x + w01 * gB1.x + w10 * gC1.x + w11 * gD1.x;          \
            v[5] = w00 * gA1.y + w01 * gB1.y + w10 * gC1.y + w11 * gD1.y;          \
            v[6] = w00 * gA1.z + w01 * gB1.z + w10 * gC1.z + w11 * gD1.z;          \
            v[7] = w00 * gA1.w + w01 * gB1.w + w10 * gC1.w + w11 * gD1.w;          \
            short8 Ah, Al;                                                         \
            _Pragma("unroll")                                                      \
            for (int j = 0; j < 8; ++j) {                                          \
                unsigned short hb = bf16_rne_bits(v[j]);                           \
                Ah[j] = (short)hb;                                                 \
                Al[j] = (short)bf16_rne_bits(v[j] - bf16_bits_to_f32(hb));         \
            }                                                                      \
            short8 Bh[8], Bl[8];                                                   \
            _Pragma("unroll")                                                      \
            for (int n = 0; n < 8; ++n) {                                          \
                size_t bi = (size_t)(((t * 4 + ks) * 8) + n) * 64;                 \
                Bh[n] = bhp[bi];                                                   \
                Bl[n] = blp[bi];                                                   \
            }                                                                      \
            _Pragma("unroll")                                                      \
            for (int n = 0; n < 8; ++n)                                            \
                acc[n] = __builtin_amdgcn_mfma_f32_16x16x32_bf16(Ah, Bh[n], acc[n], 0, 0, 0); \
            _Pragma("unroll")                                                      \
            for (int n = 0; n < 8; ++n)                                            \
                acc[n] = __builtin_amdgcn_mfma_f32_16x16x32_bf16(Ah, Bl[n], acc[n], 0, 0, 0); \
            _Pragma("unroll")                                                      \
            for (int n = 0; n < 8; ++n)                                            \
                acc[n] = __builtin_amdgcn_mfma_f32_16x16x32_bf16(Al, Bh[n], acc[n], 0, 0, 0); \
        }
        KSTEP(0, a0A, a0B, b0A, b0B, c0A, c0B, d0A, d0B)
        KSTEP(1, a1A, a1B, b1A, b1B, c1A, c1B, d1A, d1B)
        KSTEP(2, a2A, a2B, b2A, b2B, c2A, c2B, d2A, d2B)
        KSTEP(3, a3A, a3B, b3A, b3B, c3A, c3B, d3A, d3B)
#undef KSTEP
    }

    // ---- epilogue: transpose through LDS for coalesced 64-px stores ----
#pragma unroll
    for (int n = 0; n < 8; ++n) {
        int o = n * 16 + l15;
#pragma unroll
        for (int rr = 0; rr < 4; ++rr) {
            int px = wave * 16 + lhi * 4 + rr;
            epi[o * 65 + px] = acc[n][rr];
        }
    }
    __syncthreads();
    int p_blk = blk * 64;                // 64 px contiguous within one h-row
    int bb = p_blk >> 14, hw = p_blk & 16383;
    float* ob = out + (size_t)bb * CO * HW + hw;
    for (int i = tid; i < CO * 64; i += 256) {
        int o  = i >> 6;
        int px = i & 63;
        __builtin_nontemporal_store(epi[o * 65 + px] + b_main[o],
                                    &ob[(size_t)o * HW + px]);
    }
}

// ---------------------------------------------------------------------------
extern "C" void kernel_launch(void* const* d_in, const int* in_sizes, int n_in,
                              void* d_out, int out_size, void* d_ws, size_t ws_size,
                              hipStream_t stream) {
    const float* x      = (const float*)d_in[0];
    const float* w_off  = (const float*)d_in[1];
    const float* b_off  = (const float*)d_in[2];
    const float* w_main = (const float*)d_in[3];
    const float* b_main = (const float*)d_in[4];
    float* out = (float*)d_out;

    // workspace layout (bytes):
    //  xt 33,554,432 | coords 4,718,592 | wofrag 2x73,728 | wfrag 2x294,912
    char* base = (char*)d_ws;
    float*  xt     = (float*)base;
    float2* coords = (float2*)(base + 33554432);
    unsigned short* wofh = (unsigned short*)(base + 33554432 + 4718592);
    unsigned short* wofl = wofh + 9 * 4 * 2 * 512;
    unsigned short* wfh  = wofl + 9 * 4 * 2 * 512;
    unsigned short* wfl  = wfh + (size_t)CO * KTOT;

    k_transpose<<<dim3(HW / 32, CI / 32, Bb), dim3(32, 8), 0, stream>>>(x, xt);
    k_weights<<<576, 256, 0, stream>>>(w_off, w_main, wofh, wofl, wfh, wfl);
    k_offsets<<<Bb * Hh * (Ww / 32), 256, 0, stream>>>(xt, wofh, wofl, b_off, coords);
    k_fused<<<Bb * HW / 64, 256, 0, stream>>>(xt, coords, wfh, wfl, b_main, out);
}

// Round 14
// 276.773 us; speedup vs baseline: 1.6116x; 1.4379x over previous
//
#include <hip/hip_runtime.h>
#include <cstddef>

// Problem constants (match reference)
#define Bb   4
#define CI   128
#define CO   128
#define Hh   128
#define Ww   128
#define HW   (Hh*Ww)
#define NOFF 18      // 2*K*K
#define NTAP 9       // K*K
#define KTOT (NTAP*CI)   // 1152
#define NSTEP 36     // K-steps of 32: NTAP*4

typedef short short8 __attribute__((ext_vector_type(8)));
typedef _Float16 half8 __attribute__((ext_vector_type(8)));
typedef float floatx4 __attribute__((ext_vector_type(4)));

// bf16 RNE split helpers (no NaN/inf in this data)
__device__ inline unsigned short bf16_rne_bits(float f) {
    unsigned u = __float_as_uint(f);
    unsigned r = u + 0x7FFFu + ((u >> 16) & 1u);
    return (unsigned short)(r >> 16);
}
__device__ inline float bf16_bits_to_f32(unsigned short h) {
    return __uint_as_float((unsigned)h << 16);
}
__device__ inline unsigned short f32_to_f16_bits(float f) {
    union { _Float16 h; unsigned short u; } cv;
    cv.h = (_Float16)f;            // RNE
    return cv.u;
}

// ---------------------------------------------------------------------------
// K0: transpose x NCHW -> NHWC
// ---------------------------------------------------------------------------
__global__ __launch_bounds__(256) void k_transpose(const float* __restrict__ x,
                                                   float* __restrict__ xt) {
    __shared__ float tile[32][33];
    int b  = blockIdx.z;
    int c0 = blockIdx.y * 32;
    int p0 = blockIdx.x * 32;
    int tx = threadIdx.x;
    int ty = threadIdx.y;
    const float* xb  = x  + (size_t)b * CI * HW;
    float*       xtb = xt + (size_t)b * HW * CI;
#pragma unroll
    for (int i = 0; i < 4; ++i) {
        int c = c0 + ty + 8 * i;
        tile[ty + 8 * i][tx] = xb[(size_t)c * HW + p0 + tx];
    }
    __syncthreads();
#pragma unroll
    for (int i = 0; i < 4; ++i) {
        int p = p0 + ty + 8 * i;
        xtb[(size_t)p * CI + c0 + tx] = tile[tx][ty + 8 * i];
    }
}

// ---------------------------------------------------------------------------
// K0b: weight transforms.
//  wofrag (offset conv, bf16 hi/lo, N padded to 32): unchanged layout.
//  wf16 (main conv, fp16 fragment-linear): i = ((t*4+ks)*8 + g)*512 + l*8 + j
//    value = w_main[o = g*16+(l&15)][c = ks*32+(l>>4)*8+j][tap t]
// ---------------------------------------------------------------------------
__global__ __launch_bounds__(256) void k_weights(const float* __restrict__ w_off,
                                                 const float* __restrict__ w_main,
                                                 unsigned short* __restrict__ wofh,
                                                 unsigned short* __restrict__ wofl,
                                                 unsigned short* __restrict__ wf16) {
    int idx = blockIdx.x * 256 + threadIdx.x;
    int stride = gridDim.x * 256;
    for (int i = idx; i < 9 * 4 * 2 * 512; i += stride) {
        int j  = i & 7;
        int l  = (i >> 3) & 63;
        int nt = (i >> 9) & 1;
        int ks = (i >> 10) & 3;
        int t  = i >> 12;                       // 0..8  (= ky*3+kx)
        int oc = nt * 16 + (l & 15);
        int c  = ks * 32 + (l >> 4) * 8 + j;
        float f = (oc < NOFF) ? w_off[(oc * CI + c) * 9 + t] : 0.f;
        unsigned short hb = bf16_rne_bits(f);
        wofh[i] = hb;
        wofl[i] = bf16_rne_bits(f - bf16_bits_to_f32(hb));
    }
    for (int i = idx; i < CO * KTOT; i += stride) {
        int j  = i & 7;
        int l  = (i >> 3) & 63;
        int g  = (i >> 9) & 7;
        int ks = (i >> 12) & 3;
        int t  = i >> 14;
        int o  = g * 16 + (l & 15);
        int c  = ks * 32 + (l >> 4) * 8 + j;
        wf16[i] = f32_to_f16_bits(w_main[(o * CI + c) * 9 + t]);
    }
}

// ---------------------------------------------------------------------------
// K1: offset conv via split-bf16 MFMA + cumsum + sample coords (unchanged —
// coords must stay max-accuracy so floor() boundaries match the reference).
// ---------------------------------------------------------------------------
__global__ __launch_bounds__(256, 2) void k_offsets(const float* __restrict__ xt,
                                                    const unsigned short* __restrict__ wofh,
                                                    const unsigned short* __restrict__ wofl,
                                                    const float* __restrict__ b_off,
                                                    float2* __restrict__ coords) {
    __shared__ __align__(16) unsigned short ph[3 * 34 * 128];  // 26,112 B
    __shared__ __align__(16) unsigned short pl[3 * 34 * 128];  // 26,112 B
    __shared__ float raw[32][19];                              //  2,432 B
    int blk = blockIdx.x;
    int wt  = blk & 3;
    int h   = (blk >> 2) & 127;
    int b   = blk >> 9;
    int w0  = wt * 32;
    int tid  = threadIdx.x;
    int lane = tid & 63;
    int wave = tid >> 6;

    for (int i = tid; i < 3 * 34 * 64; i += 256) {
        int c2  = i & 63;
        int col = (i >> 6) % 34;
        int r   = i / (34 * 64);
        int gy  = h - 1 + r;
        int gx  = w0 - 1 + col;
        float2 v = make_float2(0.f, 0.f);
        if (gy >= 0 && gy < Hh && gx >= 0 && gx < Ww)
            v = *(const float2*)(xt + (((size_t)b * Hh + gy) * Ww + gx) * CI + c2 * 2);
        unsigned short h0 = bf16_rne_bits(v.x);
        unsigned short h1 = bf16_rne_bits(v.y);
        unsigned l0 = bf16_rne_bits(v.x - bf16_bits_to_f32(h0));
        unsigned l1 = bf16_rne_bits(v.y - bf16_bits_to_f32(h1));
        int byte = (((r * 34 + col) * 128) + c2 * 2) * 2;
        byte ^= (col & 7) << 4;
        *(unsigned*)((char*)ph + byte) = (unsigned)h0 | ((unsigned)h1 << 16);
        *(unsigned*)((char*)pl + byte) = l0 | (l1 << 16);
    }
    __syncthreads();

    int m   = wave & 1;
    int nt  = wave >> 1;
    int l15 = lane & 15, lhi = lane >> 4;
    floatx4 accE = (floatx4){0.f, 0.f, 0.f, 0.f};
    floatx4 accO = (floatx4){0.f, 0.f, 0.f, 0.f};
    const short8* bhp = (const short8*)wofh;
    const short8* blp = (const short8*)wofl;
#pragma unroll
    for (int t = 0; t < 9; ++t) {
        int ki = t / 3, kj = t % 3;
        int colb = m * 16 + l15 + kj;
        int rowoff = (ki * 34 + colb) * 256;
#pragma unroll
        for (int ks = 0; ks < 4; ++ks) {
            int abyte = (rowoff + ks * 64 + lhi * 16) ^ ((colb & 7) << 4);
            short8 Ah = *(const short8*)((char*)ph + abyte);
            short8 Al = *(const short8*)((char*)pl + abyte);
            size_t bi = (size_t)((t * 4 + ks) * 2 + nt) * 64 + lane;
            short8 Bh = bhp[bi];
            short8 Bl = blp[bi];
            floatx4& a = (ks & 1) ? accO : accE;
            a = __builtin_amdgcn_mfma_f32_16x16x32_bf16(Ah, Bh, a, 0, 0, 0);
            a = __builtin_amdgcn_mfma_f32_16x16x32_bf16(Ah, Bl, a, 0, 0, 0);
            a = __builtin_amdgcn_mfma_f32_16x16x32_bf16(Al, Bh, a, 0, 0, 0);
        }
    }
    int oc = nt * 16 + l15;
    if (oc < NOFF) {
        float bo = b_off[oc];
#pragma unroll
        for (int r = 0; r < 4; ++r) {
            int px = m * 16 + lhi * 4 + r;
            raw[px][oc] = (accE[r] + accO[r]) + bo;
        }
    }
    __syncthreads();

    for (int i = tid; i < 32 * NTAP; i += 256) {
        int px = i / NTAP;
        int t  = i % NTAP;
        int ki = t / 3, kj = t % 3;
        float offx = 0.f, offy = 0.f;
        for (int q = 0; q <= ki; ++q) offx += raw[px][q * 6 + kj * 2 + 0];
        for (int q = 0; q <= kj; ++q) offy += raw[px][ki * 6 + q * 2 + 1];
        int wg = w0 + px;
        float xg = -1.0f + 2.0f * (float)wg / 127.0f;
        float yg = -1.0f + 2.0f * (float)h  / 127.0f;
        float gx = xg + offx;
        float gy = yg + offy;
        float ix = ((gx + 1.0f) * (float)Ww - 1.0f) * 0.5f;
        float iy = ((gy + 1.0f) * (float)Hh - 1.0f) * 0.5f;
        coords[(((size_t)b * Hh + h) * Ww + wg) * NTAP + t] = make_float2(ix, iy);
    }
}

// ---------------------------------------------------------------------------
// K2a: k_sample — bilinear sample, fp16 A-fragments, FRAGMENT-LINEAR.
// Wave = 16 px x 1 tap; lane=(px, c-octet). No LDS, no barriers: pure TLP.
//  afrag idx (half8 units): (Pl*36 + tap*4 + ks)*64 + lane  — 2304 B/px.
// ---------------------------------------------------------------------------
__global__ __launch_bounds__(256) void k_sample(const float* __restrict__ xt,
                                                const float2* __restrict__ coords,
                                                unsigned short* __restrict__ af16,
                                                int q0) {
    int nb = gridDim.x;
    int blkid = blockIdx.x;
    int cpx = nb >> 3;
    blkid = (blkid & 7) * cpx + (blkid >> 3);   // XCD-contiguous remap (nb%8==0)
    int task = blkid * 4 + (threadIdx.x >> 6);
    int lane = threadIdx.x & 63;
    int Pl   = task / 9;
    int tap  = task - Pl * 9;
    int r = lane & 15, q = lane >> 4;
    int p = q0 + Pl * 16 + r;          // global pixel
    int b = p >> 14;

    float2 co = coords[(size_t)p * NTAP + tap];
    float ix = co.x, iy = co.y;
    float fx0 = floorf(ix), fy0 = floorf(iy);
    int x0 = (int)fx0, y0 = (int)fy0;
    int x1 = x0 + 1,   y1 = y0 + 1;
    float wx1 = ix - fx0, wy1 = iy - fy0;
    float wx0 = 1.f - wx1, wy0 = 1.f - wy1;
    bool vx0 = (x0 >= 0) & (x0 < Ww);
    bool vx1 = (x1 >= 0) & (x1 < Ww);
    bool vy0 = (y0 >= 0) & (y0 < Hh);
    bool vy1 = (y1 >= 0) & (y1 < Hh);
    int cx0 = min(max(x0, 0), Ww - 1), cx1 = min(max(x1, 0), Ww - 1);
    int cy0 = min(max(y0, 0), Hh - 1), cy1 = min(max(y1, 0), Hh - 1);
    float w00 = (vy0 && vx0) ? wy0 * wx0 : 0.f;
    float w01 = (vy0 && vx1) ? wy0 * wx1 : 0.f;
    float w10 = (vy1 && vx0) ? wy1 * wx0 : 0.f;
    float w11 = (vy1 && vx1) ? wy1 * wx1 : 0.f;

    const float* xb  = xt + (size_t)b * HW * CI + q * 8;
    const float* r00 = xb + ((size_t)cy0 * Ww + cx0) * CI;
    const float* r01 = xb + ((size_t)cy0 * Ww + cx1) * CI;
    const float* r10 = xb + ((size_t)cy1 * Ww + cx0) * CI;
    const float* r11 = xb + ((size_t)cy1 * Ww + cx1) * CI;
    size_t obase = ((size_t)(Pl * 36 + tap * 4) * 64 + lane) * 8;

#pragma unroll
    for (int ks = 0; ks < 4; ++ks) {
        int c = ks * 32;
        float4 a0 = *(const float4*)(r00 + c), a1 = *(const float4*)(r00 + c + 4);
        float4 b0 = *(const float4*)(r01 + c), b1 = *(const float4*)(r01 + c + 4);
        float4 c0 = *(const float4*)(r10 + c), c1 = *(const float4*)(r10 + c + 4);
        float4 d0 = *(const float4*)(r11 + c), d1 = *(const float4*)(r11 + c + 4);
        float v[8];
        v[0] = w00 * a0.x + w01 * b0.x + w10 * c0.x + w11 * d0.x;
        v[1] = w00 * a0.y + w01 * b0.y + w10 * c0.y + w11 * d0.y;
        v[2] = w00 * a0.z + w01 * b0.z + w10 * c0.z + w11 * d0.z;
        v[3] = w00 * a0.w + w01 * b0.w + w10 * c0.w + w11 * d0.w;
        v[4] = w00 * a1.x + w01 * b1.x + w10 * c1.x + w11 * d1.x;
        v[5] = w00 * a1.y + w01 * b1.y + w10 * c1.y + w11 * d1.y;
        v[6] = w00 * a1.z + w01 * b1.z + w10 * c1.z + w11 * d1.z;
        v[7] = w00 * a1.w + w01 * b1.w + w10 * c1.w + w11 * d1.w;
        short8 hv;
#pragma unroll
        for (int j = 0; j < 8; ++j) hv[j] = (short)f32_to_f16_bits(v[j]);
        *(short8*)(af16 + obase + (size_t)ks * 512) = hv;
    }
}

// ---------------------------------------------------------------------------
// K2b: k_gemm — fp16 register GEMM on pre-sampled fragments.
// Block = 32px x 128o, 4 waves (2m x 2n), wave = 16px x 64o.
// 36 K-steps x 4 MFMAs (single product), ping-pong prefetch; all loads are
// contiguous 1KB wave-loads; no LDS/barriers in main loop.
// ---------------------------------------------------------------------------
__global__ __launch_bounds__(256, 4) void k_gemm(const unsigned short* __restrict__ af16,
                                                 const unsigned short* __restrict__ wf16,
                                                 const float* __restrict__ b_main,
                                                 float* __restrict__ out, int q0) {
    __shared__ __align__(16) float epi[CO * 33];   // 16,896 B (epilogue only)
    int nb = gridDim.x;
    int cpx = nb >> 3;
    int blk = blockIdx.x;
    blk = (blk & 7) * cpx + (blk >> 3);            // XCD remap (nb%8==0)
    int tid = threadIdx.x, lane = tid & 63, wave = tid >> 6;
    int wave_n = wave & 1, wave_m = wave >> 1;
    int l15 = lane & 15, lhi = lane >> 4;
    int P = blk * 2 + wave_m;                      // local 16-px tile

    const half8* ah = (const half8*)af16 + (size_t)P * NSTEP * 64 + lane;
    const half8* bh = (const half8*)wf16 + (size_t)wave_n * 4 * 64 + lane;

    floatx4 acc[4];
#pragma unroll
    for (int n = 0; n < 4; ++n) acc[n] = (floatx4){0.f, 0.f, 0.f, 0.f};

    half8 A0, B0[4], A1, B1[4];
    A0 = ah[0];
#pragma unroll
    for (int n = 0; n < 4; ++n) B0[n] = bh[(size_t)n * 64];

#pragma unroll 2
    for (int s = 0; s < NSTEP; s += 2) {
        A1 = ah[(size_t)(s + 1) * 64];
#pragma unroll
        for (int n = 0; n < 4; ++n) B1[n] = bh[(size_t)((s + 1) * 8 + n) * 64];
#pragma unroll
        for (int n = 0; n < 4; ++n)
            acc[n] = __builtin_amdgcn_mfma_f32_16x16x32_f16(A0, B0[n], acc[n], 0, 0, 0);
        if (s + 2 < NSTEP) {
            A0 = ah[(size_t)(s + 2) * 64];
#pragma unroll
            for (int n = 0; n < 4; ++n) B0[n] = bh[(size_t)((s + 2) * 8 + n) * 64];
        }
#pragma unroll
        for (int n = 0; n < 4; ++n)
            acc[n] = __builtin_amdgcn_mfma_f32_16x16x32_f16(A1, B1[n], acc[n], 0, 0, 0);
    }

    // ---- epilogue: transpose through LDS for coalesced stores ----
#pragma unroll
    for (int n = 0; n < 4; ++n) {
        int o = wave_n * 64 + n * 16 + l15;
#pragma unroll
        for (int rr = 0; rr < 4; ++rr) {
            int px = wave_m * 16 + lhi * 4 + rr;
            epi[o * 33 + px] = acc[n][rr];
        }
    }
    __syncthreads();
    int p_blk = q0 + blk * 32;              // 32 px contiguous within one h-row
    int b = p_blk >> 14, hw = p_blk & 16383;
    float* ob = out + (size_t)b * CO * HW + hw;
    for (int i = tid; i < CO * 32; i += 256) {
        int o  = i >> 5;
        int px = i & 31;
        __builtin_nontemporal_store(epi[o * 33 + px] + b_main[o],
                                    &ob[(size_t)o * HW + px]);
    }
}

// ---------------------------------------------------------------------------
extern "C" void kernel_launch(void* const* d_in, const int* in_sizes, int n_in,
                              void* d_out, int out_size, void* d_ws, size_t ws_size,
                              hipStream_t stream) {
    const float* x      = (const float*)d_in[0];
    const float* w_off  = (const float*)d_in[1];
    const float* b_off  = (const float*)d_in[2];
    const float* w_main = (const float*)d_in[3];
    const float* b_main = (const float*)d_in[4];
    float* out = (float*)d_out;

    // workspace layout (bytes):
    //  xt 33,554,432 | coords 4,718,592 | wofrag 2x73,728 | wf16 294,912
    //  | af16 (chunked fp16 A fragments, 2304 B/px)
    char* base = (char*)d_ws;
    float*  xt     = (float*)base;
    float2* coords = (float2*)(base + 33554432);
    unsigned short* wofh = (unsigned short*)(base + 33554432 + 4718592);
    unsigned short* wofl = wofh + 9 * 4 * 2 * 512;
    unsigned short* wf16 = wofl + 9 * 4 * 2 * 512;
    size_t fixed_b = 33554432 + 4718592 + 2 * (9 * 4 * 2 * 512) * 2
                   + (size_t)CO * KTOT * 2;
    unsigned short* af16 = (unsigned short*)(base + fixed_b);

    // chunk: multiple of 2048 px, capped at 32768 (af16 75.5 MB + xt 33.5 MB
    // stays comfortably L3-resident; same-buffer reuse across chunks).
    size_t avail = (ws_size > fixed_b) ? (ws_size - fixed_b) : 0;
    long long maxpx = (long long)(avail / 2304);
    int chunk = (int)((maxpx / 2048) * 2048);
    if (chunk > 32768) chunk = 32768;
    if (chunk < 2048) chunk = 2048;          // minimum footprint fallback

    k_transpose<<<dim3(HW / 32, CI / 32, Bb), dim3(32, 8), 0, stream>>>(x, xt);
    k_weights<<<576, 256, 0, stream>>>(w_off, w_main, wofh, wofl, wf16);
    k_offsets<<<Bb * Hh * (Ww / 32), 256, 0, stream>>>(xt, wofh, wofl, b_off, coords);
    for (int q0 = 0; q0 < Bb * HW; q0 += chunk) {
        int np = Bb * HW - q0; if (np > chunk) np = chunk;
        k_sample<<<(np / 16) * 9 / 4, 256, 0, stream>>>(xt, coords, af16, q0);
        k_gemm<<<np / 32, 256, 0, stream>>>(af16, wf16, b_main, out, q0);
    }
}

// Round 15
// 216.903 us; speedup vs baseline: 2.0565x; 1.2760x over previous
//
#include <hip/hip_runtime.h>
#include <cstddef>

// Problem constants (match reference)
#define Bb   4
#define CI   128
#define CO   128
#define Hh   128
#define Ww   128
#define HW   (Hh*Ww)
#define NOFF 18      // 2*K*K
#define NTAP 9       // K*K
#define KTOT (NTAP*CI)   // 1152
#define NSTEP 36     // K-steps of 32: NTAP*4

typedef short short8 __attribute__((ext_vector_type(8)));
typedef _Float16 half8 __attribute__((ext_vector_type(8)));
typedef float floatx4 __attribute__((ext_vector_type(4)));

// bf16 RNE split helpers (no NaN/inf in this data)
__device__ inline unsigned short bf16_rne_bits(float f) {
    unsigned u = __float_as_uint(f);
    unsigned r = u + 0x7FFFu + ((u >> 16) & 1u);
    return (unsigned short)(r >> 16);
}
__device__ inline float bf16_bits_to_f32(unsigned short h) {
    return __uint_as_float((unsigned)h << 16);
}
__device__ inline unsigned short f32_to_f16_bits(float f) {
    union { _Float16 h; unsigned short u; } cv;
    cv.h = (_Float16)f;            // RNE
    return cv.u;
}

// ---------------------------------------------------------------------------
// K0: transpose x NCHW -> NHWC; emits fp32 (for k_offsets' exact coords) and
// fp16 (for k_sample's gather — halves gather bytes and instructions).
// ---------------------------------------------------------------------------
__global__ __launch_bounds__(256) void k_transpose(const float* __restrict__ x,
                                                   float* __restrict__ xt,
                                                   _Float16* __restrict__ xt16) {
    __shared__ float tile[32][33];
    int b  = blockIdx.z;
    int c0 = blockIdx.y * 32;
    int p0 = blockIdx.x * 32;
    int tx = threadIdx.x;
    int ty = threadIdx.y;
    const float* xb   = x    + (size_t)b * CI * HW;
    float*       xtb  = xt   + (size_t)b * HW * CI;
    _Float16*    xt16b = xt16 + (size_t)b * HW * CI;
#pragma unroll
    for (int i = 0; i < 4; ++i) {
        int c = c0 + ty + 8 * i;
        tile[ty + 8 * i][tx] = xb[(size_t)c * HW + p0 + tx];
    }
    __syncthreads();
#pragma unroll
    for (int i = 0; i < 4; ++i) {
        int p = p0 + ty + 8 * i;
        float v = tile[tx][ty + 8 * i];
        xtb[(size_t)p * CI + c0 + tx] = v;
        xt16b[(size_t)p * CI + c0 + tx] = (_Float16)v;
    }
}

// ---------------------------------------------------------------------------
// K0b: weight transforms.
//  wofrag (offset conv, bf16 hi/lo, N padded to 32): unchanged layout.
//  wf16 (main conv, fp16 fragment-linear): i = ((t*4+ks)*8 + g)*512 + l*8 + j
// ---------------------------------------------------------------------------
__global__ __launch_bounds__(256) void k_weights(const float* __restrict__ w_off,
                                                 const float* __restrict__ w_main,
                                                 unsigned short* __restrict__ wofh,
                                                 unsigned short* __restrict__ wofl,
                                                 unsigned short* __restrict__ wf16) {
    int idx = blockIdx.x * 256 + threadIdx.x;
    int stride = gridDim.x * 256;
    for (int i = idx; i < 9 * 4 * 2 * 512; i += stride) {
        int j  = i & 7;
        int l  = (i >> 3) & 63;
        int nt = (i >> 9) & 1;
        int ks = (i >> 10) & 3;
        int t  = i >> 12;                       // 0..8  (= ky*3+kx)
        int oc = nt * 16 + (l & 15);
        int c  = ks * 32 + (l >> 4) * 8 + j;
        float f = (oc < NOFF) ? w_off[(oc * CI + c) * 9 + t] : 0.f;
        unsigned short hb = bf16_rne_bits(f);
        wofh[i] = hb;
        wofl[i] = bf16_rne_bits(f - bf16_bits_to_f32(hb));
    }
    for (int i = idx; i < CO * KTOT; i += stride) {
        int j  = i & 7;
        int l  = (i >> 3) & 63;
        int g  = (i >> 9) & 7;
        int ks = (i >> 12) & 3;
        int t  = i >> 14;
        int o  = g * 16 + (l & 15);
        int c  = ks * 32 + (l >> 4) * 8 + j;
        wf16[i] = f32_to_f16_bits(w_main[(o * CI + c) * 9 + t]);
    }
}

// ---------------------------------------------------------------------------
// K1: offset conv via split-bf16 MFMA + cumsum + sample coords (unchanged —
// coords must stay max-accuracy so floor() boundaries match the reference).
// ---------------------------------------------------------------------------
__global__ __launch_bounds__(256, 2) void k_offsets(const float* __restrict__ xt,
                                                    const unsigned short* __restrict__ wofh,
                                                    const unsigned short* __restrict__ wofl,
                                                    const float* __restrict__ b_off,
                                                    float2* __restrict__ coords) {
    __shared__ __align__(16) unsigned short ph[3 * 34 * 128];  // 26,112 B
    __shared__ __align__(16) unsigned short pl[3 * 34 * 128];  // 26,112 B
    __shared__ float raw[32][19];                              //  2,432 B
    int blk = blockIdx.x;
    int wt  = blk & 3;
    int h   = (blk >> 2) & 127;
    int b   = blk >> 9;
    int w0  = wt * 32;
    int tid  = threadIdx.x;
    int lane = tid & 63;
    int wave = tid >> 6;

    for (int i = tid; i < 3 * 34 * 64; i += 256) {
        int c2  = i & 63;
        int col = (i >> 6) % 34;
        int r   = i / (34 * 64);
        int gy  = h - 1 + r;
        int gx  = w0 - 1 + col;
        float2 v = make_float2(0.f, 0.f);
        if (gy >= 0 && gy < Hh && gx >= 0 && gx < Ww)
            v = *(const float2*)(xt + (((size_t)b * Hh + gy) * Ww + gx) * CI + c2 * 2);
        unsigned short h0 = bf16_rne_bits(v.x);
        unsigned short h1 = bf16_rne_bits(v.y);
        unsigned l0 = bf16_rne_bits(v.x - bf16_bits_to_f32(h0));
        unsigned l1 = bf16_rne_bits(v.y - bf16_bits_to_f32(h1));
        int byte = (((r * 34 + col) * 128) + c2 * 2) * 2;
        byte ^= (col & 7) << 4;
        *(unsigned*)((char*)ph + byte) = (unsigned)h0 | ((unsigned)h1 << 16);
        *(unsigned*)((char*)pl + byte) = l0 | (l1 << 16);
    }
    __syncthreads();

    int m   = wave & 1;
    int nt  = wave >> 1;
    int l15 = lane & 15, lhi = lane >> 4;
    floatx4 accE = (floatx4){0.f, 0.f, 0.f, 0.f};
    floatx4 accO = (floatx4){0.f, 0.f, 0.f, 0.f};
    const short8* bhp = (const short8*)wofh;
    const short8* blp = (const short8*)wofl;
#pragma unroll
    for (int t = 0; t < 9; ++t) {
        int ki = t / 3, kj = t % 3;
        int colb = m * 16 + l15 + kj;
        int rowoff = (ki * 34 + colb) * 256;
#pragma unroll
        for (int ks = 0; ks < 4; ++ks) {
            int abyte = (rowoff + ks * 64 + lhi * 16) ^ ((colb & 7) << 4);
            short8 Ah = *(const short8*)((char*)ph + abyte);
            short8 Al = *(const short8*)((char*)pl + abyte);
            size_t bi = (size_t)((t * 4 + ks) * 2 + nt) * 64 + lane;
            short8 Bh = bhp[bi];
            short8 Bl = blp[bi];
            floatx4& a = (ks & 1) ? accO : accE;
            a = __builtin_amdgcn_mfma_f32_16x16x32_bf16(Ah, Bh, a, 0, 0, 0);
            a = __builtin_amdgcn_mfma_f32_16x16x32_bf16(Ah, Bl, a, 0, 0, 0);
            a = __builtin_amdgcn_mfma_f32_16x16x32_bf16(Al, Bh, a, 0, 0, 0);
        }
    }
    int oc = nt * 16 + l15;
    if (oc < NOFF) {
        float bo = b_off[oc];
#pragma unroll
        for (int r = 0; r < 4; ++r) {
            int px = m * 16 + lhi * 4 + r;
            raw[px][oc] = (accE[r] + accO[r]) + bo;
        }
    }
    __syncthreads();

    for (int i = tid; i < 32 * NTAP; i += 256) {
        int px = i / NTAP;
        int t  = i % NTAP;
        int ki = t / 3, kj = t % 3;
        float offx = 0.f, offy = 0.f;
        for (int q = 0; q <= ki; ++q) offx += raw[px][q * 6 + kj * 2 + 0];
        for (int q = 0; q <= kj; ++q) offy += raw[px][ki * 6 + q * 2 + 1];
        int wg = w0 + px;
        float xg = -1.0f + 2.0f * (float)wg / 127.0f;
        float yg = -1.0f + 2.0f * (float)h  / 127.0f;
        float gx = xg + offx;
        float gy = yg + offy;
        float ix = ((gx + 1.0f) * (float)Ww - 1.0f) * 0.5f;
        float iy = ((gy + 1.0f) * (float)Hh - 1.0f) * 0.5f;
        coords[(((size_t)b * Hh + h) * Ww + wg) * NTAP + t] = make_float2(ix, iy);
    }
}

// ---------------------------------------------------------------------------
// K2a: k_sample — bilinear sample from fp16 xt16, fp16 A-fragments out.
// Wave = 16 px x 1 tap; lane=(px, c-octet). No LDS, no barriers: pure TLP.
// Gather: 16 loads of half8 per lane (was 32 float4) — bytes and insts halved.
//  afrag idx (half8 units): (Pl*36 + tap*4 + ks)*64 + lane  — 2304 B/px.
// ---------------------------------------------------------------------------
__global__ __launch_bounds__(256) void k_sample(const _Float16* __restrict__ xt16,
                                                const float2* __restrict__ coords,
                                                unsigned short* __restrict__ af16,
                                                int q0) {
    int nb = gridDim.x;
    int blkid = blockIdx.x;
    int cpx = nb >> 3;
    blkid = (blkid & 7) * cpx + (blkid >> 3);   // XCD-contiguous remap (nb%8==0)
    int task = blkid * 4 + (threadIdx.x >> 6);
    int lane = threadIdx.x & 63;
    int Pl   = task / 9;
    int tap  = task - Pl * 9;
    int r = lane & 15, q = lane >> 4;
    int p = q0 + Pl * 16 + r;          // global pixel
    int b = p >> 14;

    float2 co = coords[(size_t)p * NTAP + tap];
    float ix = co.x, iy = co.y;
    float fx0 = floorf(ix), fy0 = floorf(iy);
    int x0 = (int)fx0, y0 = (int)fy0;
    int x1 = x0 + 1,   y1 = y0 + 1;
    float wx1 = ix - fx0, wy1 = iy - fy0;
    float wx0 = 1.f - wx1, wy0 = 1.f - wy1;
    bool vx0 = (x0 >= 0) & (x0 < Ww);
    bool vx1 = (x1 >= 0) & (x1 < Ww);
    bool vy0 = (y0 >= 0) & (y0 < Hh);
    bool vy1 = (y1 >= 0) & (y1 < Hh);
    int cx0 = min(max(x0, 0), Ww - 1), cx1 = min(max(x1, 0), Ww - 1);
    int cy0 = min(max(y0, 0), Hh - 1), cy1 = min(max(y1, 0), Hh - 1);
    float w00 = (vy0 && vx0) ? wy0 * wx0 : 0.f;
    float w01 = (vy0 && vx1) ? wy0 * wx1 : 0.f;
    float w10 = (vy1 && vx0) ? wy1 * wx0 : 0.f;
    float w11 = (vy1 && vx1) ? wy1 * wx1 : 0.f;

    const _Float16* xb  = xt16 + (size_t)b * HW * CI + q * 8;
    const _Float16* r00 = xb + ((size_t)cy0 * Ww + cx0) * CI;
    const _Float16* r01 = xb + ((size_t)cy0 * Ww + cx1) * CI;
    const _Float16* r10 = xb + ((size_t)cy1 * Ww + cx0) * CI;
    const _Float16* r11 = xb + ((size_t)cy1 * Ww + cx1) * CI;
    size_t obase = ((size_t)(Pl * 36 + tap * 4) * 64 + lane) * 8;

#pragma unroll
    for (int ks = 0; ks < 4; ++ks) {
        int c = ks * 32;
        half8 a8 = *(const half8*)(r00 + c);
        half8 b8 = *(const half8*)(r01 + c);
        half8 c8 = *(const half8*)(r10 + c);
        half8 d8 = *(const half8*)(r11 + c);
        short8 hv;
#pragma unroll
        for (int j = 0; j < 8; ++j) {
            float v = w00 * (float)a8[j] + w01 * (float)b8[j]
                    + w10 * (float)c8[j] + w11 * (float)d8[j];
            hv[j] = (short)f32_to_f16_bits(v);
        }
        *(short8*)(af16 + obase + (size_t)ks * 512) = hv;
    }
}

// ---------------------------------------------------------------------------
// K2b: k_gemm — fp16 register GEMM on pre-sampled fragments.
// Block = 32px x 128o, 4 waves (2m x 2n), wave = 16px x 64o.
// 36 K-steps x 4 MFMAs (single product), ping-pong prefetch; all loads are
// contiguous 1KB wave-loads; no LDS/barriers in main loop.
// ---------------------------------------------------------------------------
__global__ __launch_bounds__(256, 4) void k_gemm(const unsigned short* __restrict__ af16,
                                                 const unsigned short* __restrict__ wf16,
                                                 const float* __restrict__ b_main,
                                                 float* __restrict__ out, int q0) {
    __shared__ __align__(16) float epi[CO * 33];   // 16,896 B (epilogue only)
    int nb = gridDim.x;
    int cpx = nb >> 3;
    int blk = blockIdx.x;
    blk = (blk & 7) * cpx + (blk >> 3);            // XCD remap (nb%8==0)
    int tid = threadIdx.x, lane = tid & 63, wave = tid >> 6;
    int wave_n = wave & 1, wave_m = wave >> 1;
    int l15 = lane & 15, lhi = lane >> 4;
    int P = blk * 2 + wave_m;                      // local 16-px tile

    const half8* ah = (const half8*)af16 + (size_t)P * NSTEP * 64 + lane;
    const half8* bh = (const half8*)wf16 + (size_t)wave_n * 4 * 64 + lane;

    floatx4 acc[4];
#pragma unroll
    for (int n = 0; n < 4; ++n) acc[n] = (floatx4){0.f, 0.f, 0.f, 0.f};

    half8 A0, B0[4], A1, B1[4];
    A0 = ah[0];
#pragma unroll
    for (int n = 0; n < 4; ++n) B0[n] = bh[(size_t)n * 64];

#pragma unroll 2
    for (int s = 0; s < NSTEP; s += 2) {
        A1 = ah[(size_t)(s + 1) * 64];
#pragma unroll
        for (int n = 0; n < 4; ++n) B1[n] = bh[(size_t)((s + 1) * 8 + n) * 64];
#pragma unroll
        for (int n = 0; n < 4; ++n)
            acc[n] = __builtin_amdgcn_mfma_f32_16x16x32_f16(A0, B0[n], acc[n], 0, 0, 0);
        if (s + 2 < NSTEP) {
            A0 = ah[(size_t)(s + 2) * 64];
#pragma unroll
            for (int n = 0; n < 4; ++n) B0[n] = bh[(size_t)((s + 2) * 8 + n) * 64];
        }
#pragma unroll
        for (int n = 0; n < 4; ++n)
            acc[n] = __builtin_amdgcn_mfma_f32_16x16x32_f16(A1, B1[n], acc[n], 0, 0, 0);
    }

    // ---- epilogue: transpose through LDS for coalesced stores ----
#pragma unroll
    for (int n = 0; n < 4; ++n) {
        int o = wave_n * 64 + n * 16 + l15;
#pragma unroll
        for (int rr = 0; rr < 4; ++rr) {
            int px = wave_m * 16 + lhi * 4 + rr;
            epi[o * 33 + px] = acc[n][rr];
        }
    }
    __syncthreads();
    int p_blk = q0 + blk * 32;              // 32 px contiguous within one h-row
    int b = p_blk >> 14, hw = p_blk & 16383;
    float* ob = out + (size_t)b * CO * HW + hw;
    for (int i = tid; i < CO * 32; i += 256) {
        int o  = i >> 5;
        int px = i & 31;
        __builtin_nontemporal_store(epi[o * 33 + px] + b_main[o],
                                    &ob[(size_t)o * HW + px]);
    }
}

// ---------------------------------------------------------------------------
extern "C" void kernel_launch(void* const* d_in, const int* in_sizes, int n_in,
                              void* d_out, int out_size, void* d_ws, size_t ws_size,
                              hipStream_t stream) {
    const float* x      = (const float*)d_in[0];
    const float* w_off  = (const float*)d_in[1];
    const float* b_off  = (const float*)d_in[2];
    const float* w_main = (const float*)d_in[3];
    const float* b_main = (const float*)d_in[4];
    float* out = (float*)d_out;

    // workspace layout (bytes):
    //  xt 33,554,432 | xt16 16,777,216 | coords 4,718,592
    //  | wofrag 2x73,728 | wf16 294,912 | af16 (chunked, 2304 B/px)
    char* base = (char*)d_ws;
    float*    xt    = (float*)base;
    _Float16* xt16  = (_Float16*)(base + 33554432);
    float2*   coords = (float2*)(base + 33554432 + 16777216);
    unsigned short* wofh = (unsigned short*)(base + 33554432 + 16777216 + 4718592);
    unsigned short* wofl = wofh + 9 * 4 * 2 * 512;
    unsigned short* wf16 = wofl + 9 * 4 * 2 * 512;
    size_t fixed_b = 33554432 + 16777216 + 4718592
                   + 2 * (9 * 4 * 2 * 512) * 2 + (size_t)CO * KTOT * 2;
    unsigned short* af16 = (unsigned short*)(base + fixed_b);

    // chunk: multiple of 2048 px, capped at 32768 (af16 75.5 MB + xt/xt16
    // stays L3-resident; same-buffer reuse across chunks).
    size_t avail = (ws_size > fixed_b) ? (ws_size - fixed_b) : 0;
    long long maxpx = (long long)(avail / 2304);
    int chunk = (int)((maxpx / 2048) * 2048);
    if (chunk > 32768) chunk = 32768;
    if (chunk < 2048) chunk = 2048;          // minimum footprint fallback

    k_transpose<<<dim3(HW / 32, CI / 32, Bb), dim3(32, 8), 0, stream>>>(x, xt, xt16);
    k_weights<<<576, 256, 0, stream>>>(w_off, w_main, wofh, wofl, wf16);
    k_offsets<<<Bb * Hh * (Ww / 32), 256, 0, stream>>>(xt, wofh, wofl, b_off, coords);
    for (int q0 = 0; q0 < Bb * HW; q0 += chunk) {
        int np = Bb * HW - q0; if (np > chunk) np = chunk;
        k_sample<<<(np / 16) * 9 / 4, 256, 0, stream>>>(xt16, coords, af16, q0);
        k_gemm<<<np / 32, 256, 0, stream>>>(af16, wf16, b_main, out, q0);
    }
}